// Round 14
// baseline (320.524 us; speedup 1.0000x reference)
//
#include <hip/hip_runtime.h>

#define TSTEPS 2048
#define BATCH  4096
#define HID    4
#define STRIDE (BATCH*HID)    // 16384 floats per timestep slab
#define CH     32             // timesteps per chunk (barrier period)
#define NCHUNK (TSTEPS/CH)    // 64 source chunks
#define NPH    (NCHUNK+2)     // 66 phases = 3 * 22 (static xbuf slot rotation)
#define NPROBE 4096           // probe iterations (2x TSTEPS for SNR)

// Broadcast component k (0..3) to all 4 lanes of each quad via DPP quad_perm.
#define QB(v,k) __int_as_float(__builtin_amdgcn_update_dpp( \
    0, __float_as_int(v), (k)*0x55, 0xF, 0xF, true))

__device__ __forceinline__ float fast_exp2(float x) {
#if __has_builtin(__builtin_amdgcn_exp2f)
  return __builtin_amdgcn_exp2f(x);
#else
  return exp2f(x);
#endif
}
__device__ __forceinline__ float fast_rcp(float x) {
#if __has_builtin(__builtin_amdgcn_rcpf)
  return __builtin_amdgcn_rcpf(x);
#else
  return 1.0f / x;
#endif
}

// Direct global->LDS 4B load: LDS dest = base + lane*4 (wave-uniform base),
// global src per-lane. No VGPR liveness -> compiler cannot sink the prefetch.
__device__ __forceinline__ void xload(float* ldst, const float* gsrc) {
  __builtin_amdgcn_global_load_lds(
      (const __attribute__((address_space(1))) void*)gsrc,
      (__attribute__((address_space(3))) void*)ldst, 4, 0, 0);
}

// ===================== PRODUCTION KERNEL (r9, 202us) ======================
// 3-wave layer-systolic, CH=32. Wave l (=wid) owns layer l; phase c processes
// source chunk m = c - wid. Recurrence on r = 1/(1+exp2(a)), h = 1-2r folded
// into weights. h handoff through double-buffered LDS iface; ONE raw
// s_barrier per phase; lgkmcnt(0) drained before it; vmcnt counted (32),
// never drained in the loop. x staged via global_load_lds, 3-slot ring.
__global__ __launch_bounds__(192) void rnn_pipe(
    const float* __restrict__ X,    // (T, B, H)
    const float* __restrict__ H0,   // (L, B, H)
    const float* __restrict__ Wih,  // (L, H, H)
    const float* __restrict__ Whh,  // (L, H, H)
    const float* __restrict__ bih,  // (L, H)
    const float* __restrict__ bhh,  // (L, H)
    float* __restrict__ Y)          // (T, B, H)
{
  const int lane = threadIdx.x & 63;
  const int wid  = threadIdx.x >> 6;           // 0,1,2 = layer index
  const int g    = blockIdx.x * 64 + lane;     // global (b,j) unit
  const int j    = g & 3;
  const float K  = 2.8853900817779268f;        // 2*log2(e)

  __shared__ float iface[2][2][CH][64];        // 32 KB
  __shared__ float xbuf[3][CH][64];            // 24 KB

  float wi[HID], whp[HID], cb;
  {
    float wsum = 0.0f;
#pragma unroll
    for (int k = 0; k < HID; ++k) {
      float whh = Whh[(wid*HID + j)*HID + k];
      whp[k] = -2.0f * K * whh;
      wsum  += whh;
      wi[k]  = Wih[(wid*HID + j)*HID + k] * K;
    }
    cb = (bih[wid*HID + j] + bhh[wid*HID + j] + wsum) * K;
  }

  float r = 0.5f * (1.0f - H0[wid*STRIDE + g]);   // h = 1 - 2r

  const float* __restrict__ xp = X + g;

  if (wid == 0) {
    __builtin_amdgcn_sched_barrier(0);
    asm volatile("s_waitcnt vmcnt(0)" ::: "memory");
#pragma unroll
    for (int u = 0; u < CH; ++u)
      xload(&xbuf[0][u][0], xp + (size_t)(0*CH + u) * STRIDE);
#pragma unroll
    for (int u = 0; u < CH; ++u)
      xload(&xbuf[1][u][0], xp + (size_t)(1*CH + u) * STRIDE);
  }

  auto phase = [&](int c, int slot) {
    if (c >= wid && c <= NCHUNK - 1 + wid) {
      const int m    = c - wid;
      const int base = m * CH;
      const int par  = m & 1;

      const float* vsrc;
      if (wid == 0) {
        asm volatile("s_waitcnt vmcnt(32)" ::: "memory");
        __builtin_amdgcn_sched_barrier(0);
        vsrc = &xbuf[slot][0][0];
      } else {
        vsrc = &iface[wid-1][par][0][0];
      }

      float ai[CH];
#pragma unroll
      for (int u = 0; u < CH; ++u) {
        float v = vsrc[u*64 + lane];
        float a = cb;
        a = fmaf(QB(v, 0), wi[0], a);
        a = fmaf(QB(v, 1), wi[1], a);
        a = fmaf(QB(v, 2), wi[2], a);
        a = fmaf(QB(v, 3), wi[3], a);
        ai[u] = a;
      }

      if (wid == 0) {
#pragma unroll
        for (int u = 0; u < CH; ++u) {
          int tn = base + 2*CH + u;
          if (tn > TSTEPS - 1) tn = TSTEPS - 1;
          xload(&xbuf[(slot+2)%3][u][0], xp + (size_t)tn * STRIDE);
        }
      }

#pragma unroll
      for (int u = 0; u < CH; ++u) {
        float t0 = fmaf(QB(r, 0), whp[0], ai[u]);
        float t1 =      QB(r, 1) * whp[1];
        t0 = fmaf(QB(r, 2), whp[2], t0);
        t1 = fmaf(QB(r, 3), whp[3], t1);
        float e = fast_exp2(t0 + t1);
        r = fast_rcp(e + 1.0f);
        float h = fmaf(-2.0f, r, 1.0f);
        if (wid <= 1) {
          iface[wid][par][u][lane] = h;
        } else {
          Y[(size_t)(base + u) * STRIDE + g] = h;
        }
      }
    }

    __builtin_amdgcn_sched_barrier(0);
    asm volatile("s_waitcnt lgkmcnt(0)" ::: "memory");
    __builtin_amdgcn_s_barrier();
    __builtin_amdgcn_sched_barrier(0);
  };

  for (int cb2 = 0; cb2 < NPH; cb2 += 3) {
    phase(cb2 + 0, 0);
    phase(cb2 + 1, 1);
    phase(cb2 + 2, 2);
  }
}

// ===================== ABLATION PROBE (recurrence only) ===================
// Pure serial recurrence chain, exactly the r9 per-step body: 4x DPP quad-dot
// -> exp2 -> add -> rcp. No LDS, no barriers, no staging, no stores in loop.
// Runtime weights (from X) defeat constant folding; asm sink defeats DCE.
// NPROBE=4096 iterations; per-step cost = T_probe * 2.4e3 / 4096 cycles.
__global__ __launch_bounds__(192) void rec_probe(
    const float* __restrict__ X, float* __restrict__ ws, int do_store)
{
  const int tid = blockIdx.x * 192 + threadIdx.x;
  const int idx = tid & 1023;
  float w0 = X[idx];
  float w1 = X[idx + 1024];
  float w2 = X[idx + 2048];
  float w3 = X[idx + 3072];
  float c  = X[idx + 4096];
  float r  = X[idx + 5120];

  for (int t = 0; t < NPROBE / 8; ++t) {
#pragma unroll
    for (int u = 0; u < 8; ++u) {
      float t0 = fmaf(QB(r, 0), w0, c);
      float t1 =      QB(r, 1) * w1;
      t0 = fmaf(QB(r, 2), w2, t0);
      t1 = fmaf(QB(r, 3), w3, t1);
      float e = fast_exp2(t0 + t1);
      r = fast_rcp(e + 1.0f);
    }
  }
  asm volatile("" :: "v"(r));          // keep the chain live (rule #17)
  if (do_store) ws[tid & 16383] = r;   // scratch only; guarded by host flag
}

extern "C" void kernel_launch(void* const* d_in, const int* in_sizes, int n_in,
                              void* d_out, int out_size, void* d_ws, size_t ws_size,
                              hipStream_t stream) {
  const float* X   = (const float*)d_in[0];
  const float* H0  = (const float*)d_in[1];
  const float* Wih = (const float*)d_in[2];
  const float* Whh = (const float*)d_in[3];
  const float* bih = (const float*)d_in[4];
  const float* bhh = (const float*)d_in[5];
  float* Y = (float*)d_out;

  // Production: 256 blocks x 192 threads (3 layer-waves per CU).
  rnn_pipe<<<dim3(STRIDE / 64), dim3(192), 0, stream>>>(X, H0, Wih, Whh, bih, bhh, Y);

  // Ablation probe: same grid shape; writes only to scratch.
  int do_store = (ws_size >= 16384 * sizeof(float)) ? 1 : 0;
  rec_probe<<<dim3(STRIDE / 64), dim3(192), 0, stream>>>(X, (float*)d_ws, do_store);
}

// Round 15
// 115.003 us; speedup vs baseline: 2.7871x; 2.7871x over previous
//
#include <hip/hip_runtime.h>

#define TSTEPS 2048
#define BATCH  4096
#define HID    4
#define STRIDE (BATCH*HID)    // 16384 floats per timestep slab
#define CH     32             // timesteps per chunk (barrier period)
#define NCHUNK (TSTEPS/CH)    // 64 source chunks
#define NPH    69             // >= NCHUNK+3 = 67, rounded to 3*23 for slots

// Broadcast component k (0..3) to all 4 lanes of each quad via DPP quad_perm.
#define QB(v,k) __int_as_float(__builtin_amdgcn_update_dpp( \
    0, __float_as_int(v), (k)*0x55, 0xF, 0xF, true))

__device__ __forceinline__ float fast_exp2(float x) {
#if __has_builtin(__builtin_amdgcn_exp2f)
  return __builtin_amdgcn_exp2f(x);
#else
  return exp2f(x);
#endif
}
__device__ __forceinline__ float fast_rcp(float x) {
#if __has_builtin(__builtin_amdgcn_rcpf)
  return __builtin_amdgcn_rcpf(x);
#else
  return 1.0f / x;
#endif
}

// Direct global->LDS 4B load (wave-uniform LDS base + lane*4).
__device__ __forceinline__ void xload(float* ldst, const float* gsrc) {
  __builtin_amdgcn_global_load_lds(
      (const __attribute__((address_space(1))) void*)gsrc,
      (__attribute__((address_space(3))) void*)ldst, 4, 0, 0);
}

// 4-wave producer/consumer layer pipeline (r14 probe: chain = 69 cyc/step;
// this structure fits ALL non-chain work under the chain stalls).
//   wave0            : x staging (global_load_lds ring) + ai compute for
//                      layer0 -> iface[0]. No recurrence.
//   wave l (1..3)    : serial tail of layer l-1 (reads iface[l-2... i.e.
//                      iface[wid-1]) AND computes next layer's ai (off its
//                      critical path) -> iface[wid]; wave3 stores Y.
//   wave l at phase p handles chunk m = p - l (wave0: m = p).
// Protocol identical to the verified r9 kernel: double-buffered interfaces
// (slot = m&1), ONE raw s_barrier per phase, lgkmcnt(0) drained before it,
// vmcnt counted (32) and never drained in the loop.
// Recurrence on r = 1/(1+exp2(a)), h = 1-2r folded into weights:
//   a = ai + whp.r_quad ; whp = -2K*Whh ; ai = cb + win.(input)
//   win = K*Wih, cb = K*(bih+bhh+Whh.1), K = 2*log2(e).
__global__ __launch_bounds__(256) void rnn_pipe4(
    const float* __restrict__ X,    // (T, B, H)
    const float* __restrict__ H0,   // (L, B, H)
    const float* __restrict__ Wih,  // (L, H, H)
    const float* __restrict__ Whh,  // (L, H, H)
    const float* __restrict__ bih,  // (L, H)
    const float* __restrict__ bhh,  // (L, H)
    float* __restrict__ Y)          // (T, B, H)
{
  const int lane = threadIdx.x & 63;
  const int wid  = threadIdx.x >> 6;           // 0 = producer; 1..3 = layers
  const int g    = blockIdx.x * 64 + lane;     // global (b,j) unit
  const int j    = g & 3;
  const float K  = 2.8853900817779268f;        // 2*log2(e)

  __shared__ float iface[3][2][CH][64];        // 48 KB: ai handoff l -> l+1
  __shared__ float xbuf[3][CH][64];            // 24 KB: x staging ring

  // Per-wave weights.
  //   wid>=1: whp = -2K*Whh[wid-1] row j (tail of layer wid-1), r init.
  //   wid<=2: win = K*Wih[wid] row j, cbn = K*(b[wid]+Whh[wid].1) (next ai).
  float whp[HID], win[HID], cbn = 0.0f, r = 0.0f;
  {
    const int Lt = wid - 1;                    // tail layer
    const int Ln = wid;                        // next-ai layer
    if (wid >= 1) {
#pragma unroll
      for (int k = 0; k < HID; ++k)
        whp[k] = -2.0f * K * Whh[(Lt*HID + j)*HID + k];
      r = 0.5f * (1.0f - H0[Lt*STRIDE + g]);   // h = 1 - 2r
    }
    if (wid <= 2) {
      float wsum = 0.0f;
#pragma unroll
      for (int k = 0; k < HID; ++k) {
        win[k] = K * Wih[(Ln*HID + j)*HID + k];
        wsum  += Whh[(Ln*HID + j)*HID + k];
      }
      cbn = K * (bih[Ln*HID + j] + bhh[Ln*HID + j] + wsum);
    }
  }

  const float* __restrict__ xp = X + g;

  // Prime the x pipeline: chunks 0,1 -> slots 0,1 (64 outstanding loads).
  if (wid == 0) {
    __builtin_amdgcn_sched_barrier(0);
    asm volatile("s_waitcnt vmcnt(0)" ::: "memory");  // clean vmcnt baseline
#pragma unroll
    for (int u = 0; u < CH; ++u)
      xload(&xbuf[0][u][0], xp + (size_t)(0*CH + u) * STRIDE);
#pragma unroll
    for (int u = 0; u < CH; ++u)
      xload(&xbuf[1][u][0], xp + (size_t)(1*CH + u) * STRIDE);
  }

  auto phase = [&](int p, int slot) {
    if (wid == 0) {
      if (p <= NCHUNK - 1) {                    // chunk m = p
        const int par = p & 1;
        // oldest 32 loads (this chunk) have landed in xbuf[slot]
        asm volatile("s_waitcnt vmcnt(32)" ::: "memory");
        __builtin_amdgcn_sched_barrier(0);
        // batch-read x into regs (LDS latency paid once)
        float xv[CH];
#pragma unroll
        for (int u = 0; u < CH; ++u) xv[u] = xbuf[slot][u][lane];
        __builtin_amdgcn_sched_barrier(0);
        // layer-0 ai for all 32 steps -> iface[0]
#pragma unroll
        for (int u = 0; u < CH; ++u) {
          float a = cbn;
          a = fmaf(QB(xv[u], 0), win[0], a);
          a = fmaf(QB(xv[u], 1), win[1], a);
          a = fmaf(QB(xv[u], 2), win[2], a);
          a = fmaf(QB(xv[u], 3), win[3], a);
          iface[0][par][u][lane] = a;
        }
        // refill: chunk p+2 -> slot (slot+2)%3 (always 32 issues; clamped
        // tail loads land but are never consumed -> vmcnt invariant exact)
#pragma unroll
        for (int u = 0; u < CH; ++u) {
          int tn = (p + 2) * CH + u;
          if (tn > TSTEPS - 1) tn = TSTEPS - 1;
          xload(&xbuf[(slot+2)%3][u][0], xp + (size_t)tn * STRIDE);
        }
      }
    } else {
      const int m = p - wid;                    // source chunk for this wave
      if (m >= 0 && m <= NCHUNK - 1) {
        const int par = m & 1;
        // batch-read this chunk's ai into regs
        float av[CH];
#pragma unroll
        for (int u = 0; u < CH; ++u) av[u] = iface[wid-1][par][u][lane];
        __builtin_amdgcn_sched_barrier(0);
        if (wid <= 2) {
          // tail of layer wid-1  +  ai of layer wid (off critical path)
#pragma unroll
          for (int u = 0; u < CH; ++u) {
            float t0 = fmaf(QB(r, 0), whp[0], av[u]);
            float t1 =      QB(r, 1) * whp[1];
            t0 = fmaf(QB(r, 2), whp[2], t0);
            t1 = fmaf(QB(r, 3), whp[3], t1);
            float e = fast_exp2(t0 + t1);
            r = fast_rcp(e + 1.0f);
            float h = fmaf(-2.0f, r, 1.0f);     // off-chain
            float a = cbn;
            a = fmaf(QB(h, 0), win[0], a);
            a = fmaf(QB(h, 1), win[1], a);
            a = fmaf(QB(h, 2), win[2], a);
            a = fmaf(QB(h, 3), win[3], a);
            iface[wid][par][u][lane] = a;
          }
        } else {
          // final layer: tail + Y store
          const int base = m * CH;
#pragma unroll
          for (int u = 0; u < CH; ++u) {
            float t0 = fmaf(QB(r, 0), whp[0], av[u]);
            float t1 =      QB(r, 1) * whp[1];
            t0 = fmaf(QB(r, 2), whp[2], t0);
            t1 = fmaf(QB(r, 3), whp[3], t1);
            float e = fast_exp2(t0 + t1);
            r = fast_rcp(e + 1.0f);
            Y[(size_t)(base + u) * STRIDE + g] = fmaf(-2.0f, r, 1.0f);
          }
        }
      }
    }

    // phase boundary: drain LDS ops only (NOT vmcnt), then raw barrier.
    __builtin_amdgcn_sched_barrier(0);
    asm volatile("s_waitcnt lgkmcnt(0)" ::: "memory");
    __builtin_amdgcn_s_barrier();
    __builtin_amdgcn_sched_barrier(0);
  };

  for (int p = 0; p < NPH; p += 3) {   // 69 = 3 * 23, static xbuf slots
    phase(p + 0, 0);
    phase(p + 1, 1);
    phase(p + 2, 2);
  }

  // drain outstanding (clamped-tail) staging loads before LDS dealloc
  if (wid == 0) asm volatile("s_waitcnt vmcnt(0)" ::: "memory");
}

extern "C" void kernel_launch(void* const* d_in, const int* in_sizes, int n_in,
                              void* d_out, int out_size, void* d_ws, size_t ws_size,
                              hipStream_t stream) {
  const float* X   = (const float*)d_in[0];
  const float* H0  = (const float*)d_in[1];
  const float* Wih = (const float*)d_in[2];
  const float* Whh = (const float*)d_in[3];
  const float* bih = (const float*)d_in[4];
  const float* bhh = (const float*)d_in[5];
  float* Y = (float*)d_out;

  // 256 blocks x 256 threads: producer wave + 3 layer waves on 4 SIMDs/CU.
  rnn_pipe4<<<dim3(STRIDE / 64), dim3(256), 0, stream>>>(X, H0, Wih, Whh, bih, bhh, Y);
}